// Round 1
// baseline (623.725 us; speedup 1.0000x reference)
//
#include <hip/hip_runtime.h>
#include <hip/hip_fp16.h>

#define D 64
#define NKR 16
#define NB 1024
#define NL 8
#define LSTR 72   // padded LDS row stride (elements); 144B = 36 dwords -> 4-bank shift/row

typedef __attribute__((ext_vector_type(8))) _Float16 half8;
typedef __attribute__((ext_vector_type(4))) float f32x4;
typedef __attribute__((ext_vector_type(4))) int i32x4;

static __device__ __forceinline__ half8 neg8(half8 x) {
    i32x4 u = __builtin_bit_cast(i32x4, x);
    u = u ^ (int)0x80008000;
    return __builtin_bit_cast(half8, u);
}

union Pack4 { _Float16 h[4]; uint2 u; };

// kraus fp32 -> fp16, layout [L][K][2][64][64] (plane 0 = re, 1 = im)
__global__ void kconv_kernel(const float* __restrict__ re, const float* __restrict__ im,
                             _Float16* __restrict__ out) {
    int plane = blockIdx.y;
    int idx = blockIdx.x * blockDim.x + threadIdx.x;   // 0..131071, 4 elems each
    const float* src = plane ? im : re;
    float4 v = ((const float4*)src)[idx];
    int e = idx * 4;
    int lk = e >> 12;
    int rem = e & 4095;
    Pack4 p;
    p.h[0] = (_Float16)v.x; p.h[1] = (_Float16)v.y;
    p.h[2] = (_Float16)v.z; p.h[3] = (_Float16)v.w;
    *(uint2*)(out + ((size_t)lk * 2 + plane) * 4096 + rem) = p.u;
}

// state fp32 -> fp16 transposed: out[b][plane][l][j] = state[b][j][l]
__global__ void sconv_kernel(const float* __restrict__ re, const float* __restrict__ im,
                             _Float16* __restrict__ out) {
    __shared__ float tile[64][65];
    int b = blockIdx.x;
    int t = threadIdx.x;
    for (int plane = 0; plane < 2; ++plane) {
        const float* src = (plane ? im : re) + (size_t)b * 4096;
        __syncthreads();
        #pragma unroll
        for (int i = 0; i < 16; ++i) {
            int e = t + 256 * i;
            tile[e >> 6][e & 63] = src[e];
        }
        __syncthreads();
        _Float16* o = out + ((size_t)b * 2 + plane) * 4096;
        #pragma unroll
        for (int i = 0; i < 16; ++i) {
            int e = t + 256 * i;            // e = l*64 + j
            o[e] = (_Float16)tile[e & 63][e >> 6];
        }
    }
}

// One block per b. rho_in layout [b][plane][l][j] = rho^T (fp16).
// Per kraus k: stage1 Tt = rho^T * K^T (A1 = rho^T hoisted in regs, B1 = K rows),
// write T row-major to LDS; stage2 rho_new = T * K^dagger, accumulate fp32.
__global__ __launch_bounds__(256, 4) void layer_kernel(
    const _Float16* __restrict__ rho_in,
    _Float16* __restrict__ rho_out,
    float* __restrict__ final_out,
    const _Float16* __restrict__ kraus,   // this layer: [K][2][64][64]
    int last)
{
    __shared__ __align__(16) _Float16 Klds[2][D][LSTR];
    __shared__ __align__(16) _Float16 Trow[2][D][LSTR];

    const int b    = blockIdx.x;
    const int t    = threadIdx.x;
    const int wv   = t >> 6;
    const int lane = t & 63;
    const int quad = lane >> 4;
    const int l15  = lane & 15;

    // ---- hoisted A1 fragments: rho^T rows l in [16*wv, 16*wv+16) ----
    half8 a1re[2], a1im[2], a1imn[2];
    {
        const _Float16* rb = rho_in + (size_t)b * 2 * D * D;
        const int row = 16 * wv + l15;        // l
        #pragma unroll
        for (int c = 0; c < 2; ++c) {
            const int col = 32 * c + 8 * quad; // j
            a1re[c]  = *(const half8*)(rb + row * D + col);
            a1im[c]  = *(const half8*)(rb + D * D + row * D + col);
            a1imn[c] = neg8(a1im[c]);
        }
    }

    f32x4 accRe[4] = {{0,0,0,0},{0,0,0,0},{0,0,0,0},{0,0,0,0}};
    f32x4 accIm[4] = {{0,0,0,0},{0,0,0,0},{0,0,0,0},{0,0,0,0}};

    #pragma unroll 1
    for (int k = 0; k < NKR; ++k) {
        // ---- stage K_k into padded LDS ----
        const uint4* kg = (const uint4*)(kraus + (size_t)k * 2 * D * D); // 1024 x 16B
        #pragma unroll
        for (int r = 0; r < 4; ++r) {
            int idx = t + 256 * r;            // 16B chunk id
            int e0  = idx * 8;                // element offset
            int plane = e0 >> 12;
            int rem   = e0 & 4095;
            int row = rem >> 6, col = rem & 63;
            *(uint4*)&Klds[plane][row][col] = kg[idx];
        }
        __syncthreads();

        // ---- stage 1: Tt = rho^T * K^T ; wave handles l-strip 16*wv ----
        #pragma unroll
        for (int ti = 0; ti < 4; ++ti) {
            f32x4 dre = {0,0,0,0}, dim = {0,0,0,0};
            #pragma unroll
            for (int c = 0; c < 2; ++c) {
                half8 bre = *(const half8*)&Klds[0][16 * ti + l15][32 * c + 8 * quad];
                half8 bim = *(const half8*)&Klds[1][16 * ti + l15][32 * c + 8 * quad];
                dre = __builtin_amdgcn_mfma_f32_16x16x32_f16(a1re[c],  bre, dre, 0, 0, 0);
                dre = __builtin_amdgcn_mfma_f32_16x16x32_f16(a1imn[c], bim, dre, 0, 0, 0);
                dim = __builtin_amdgcn_mfma_f32_16x16x32_f16(a1re[c],  bim, dim, 0, 0, 0);
                dim = __builtin_amdgcn_mfma_f32_16x16x32_f16(a1im[c],  bre, dim, 0, 0, 0);
            }
            // D1: col i = 16*ti + l15, rows l = 16*wv + 4*quad + r  -> Trow[i][l]
            const int i  = 16 * ti + l15;
            const int l0 = 16 * wv + 4 * quad;
            Pack4 pr, pi;
            #pragma unroll
            for (int r = 0; r < 4; ++r) { pr.h[r] = (_Float16)dre[r]; pi.h[r] = (_Float16)dim[r]; }
            *(uint2*)&Trow[0][i][l0] = pr.u;
            *(uint2*)&Trow[1][i][l0] = pi.u;
        }
        __syncthreads();

        // ---- stage 2: rho_new += T * K^dagger ; wave handles i-strip 16*wv ----
        #pragma unroll
        for (int c = 0; c < 2; ++c) {
            half8 are  = *(const half8*)&Trow[0][16 * wv + l15][32 * c + 8 * quad];
            half8 aim  = *(const half8*)&Trow[1][16 * wv + l15][32 * c + 8 * quad];
            half8 aren = neg8(are);
            #pragma unroll
            for (int tm = 0; tm < 4; ++tm) {
                half8 bre = *(const half8*)&Klds[0][16 * tm + l15][32 * c + 8 * quad];
                half8 bim = *(const half8*)&Klds[1][16 * tm + l15][32 * c + 8 * quad];
                accRe[tm] = __builtin_amdgcn_mfma_f32_16x16x32_f16(are,  bre, accRe[tm], 0, 0, 0);
                accRe[tm] = __builtin_amdgcn_mfma_f32_16x16x32_f16(aim,  bim, accRe[tm], 0, 0, 0);
                accIm[tm] = __builtin_amdgcn_mfma_f32_16x16x32_f16(aim,  bre, accIm[tm], 0, 0, 0);
                accIm[tm] = __builtin_amdgcn_mfma_f32_16x16x32_f16(aren, bim, accIm[tm], 0, 0, 0);
            }
        }
        __syncthreads();   // protect Klds/Trow before next iteration's writes
    }

    // ---- epilogue: D2 lane col m = 16*tm + l15, rows i = 16*wv + 4*quad + r ----
    if (!last) {
        _Float16* ob = rho_out + (size_t)b * 2 * D * D;
        const int i0 = 16 * wv + 4 * quad;
        #pragma unroll
        for (int tm = 0; tm < 4; ++tm) {
            const int m = 16 * tm + l15;
            Pack4 pr, pi;
            #pragma unroll
            for (int r = 0; r < 4; ++r) { pr.h[r] = (_Float16)accRe[tm][r]; pi.h[r] = (_Float16)accIm[tm][r]; }
            *(uint2*)(ob + m * D + i0)         = pr.u;   // rho_new^T[m][i]
            *(uint2*)(ob + D * D + m * D + i0) = pi.u;
        }
    } else {
        float* o0 = final_out + (size_t)b * 4096;            // [0][b][i][m]
        float* o1 = final_out + (size_t)(NB + b) * 4096;     // [1][b][i][m]
        #pragma unroll
        for (int tm = 0; tm < 4; ++tm) {
            const int m = 16 * tm + l15;
            #pragma unroll
            for (int r = 0; r < 4; ++r) {
                const int i = 16 * wv + 4 * quad + r;
                o0[i * D + m] = accRe[tm][r];
                o1[i * D + m] = accIm[tm][r];
            }
        }
    }
}

extern "C" void kernel_launch(void* const* d_in, const int* in_sizes, int n_in,
                              void* d_out, int out_size, void* d_ws, size_t ws_size,
                              hipStream_t stream) {
    const float* state_re = (const float*)d_in[0];
    const float* state_im = (const float*)d_in[1];
    const float* kraus_re = (const float*)d_in[2];
    const float* kraus_im = (const float*)d_in[3];

    _Float16* kraus_h = (_Float16*)d_ws;                         // 2 MB in ws
    // ping-pong rho buffers live inside d_out (2 x 16 MB = out_size exactly).
    // Safe: each layer reads its input only in the hoisted prologue (drained by
    // the first __syncthreads) and writes only in the epilogue; last layer reads
    // bufB while writing the full fp32 output (block-local, read-before-write).
    _Float16* bufA = (_Float16*)d_out;
    _Float16* bufB = (_Float16*)((char*)d_out + (size_t)NB * 2 * D * D * sizeof(_Float16));
    float* fout = (float*)d_out;

    kconv_kernel<<<dim3(512, 2), 256, 0, stream>>>(kraus_re, kraus_im, kraus_h);
    sconv_kernel<<<NB, 256, 0, stream>>>(state_re, state_im, bufA);

    for (int l = 0; l < NL; ++l) {
        const _Float16* in = (l & 1) ? bufB : bufA;
        _Float16* out      = (l & 1) ? bufA : bufB;
        layer_kernel<<<NB, 256, 0, stream>>>(in, out, fout,
                                             kraus_h + (size_t)l * NKR * 2 * D * D,
                                             (l == NL - 1) ? 1 : 0);
    }
}

// Round 2
// 612.327 us; speedup vs baseline: 1.0186x; 1.0186x over previous
//
#include <hip/hip_runtime.h>
#include <hip/hip_fp16.h>

#define D 64
#define NKR 16
#define NB 1024
#define NL 8
#define LSTR 72   // padded LDS row stride (elements); 144B keeps 16B alignment, 4-bank shift/row

typedef __attribute__((ext_vector_type(8))) _Float16 half8;
typedef __attribute__((ext_vector_type(16))) float f32x16;
typedef __attribute__((ext_vector_type(4))) int i32x4;

static __device__ __forceinline__ half8 neg8(half8 x) {
    i32x4 u = __builtin_bit_cast(i32x4, x);
    u = u ^ (int)0x80008000;
    return __builtin_bit_cast(half8, u);
}

union Pack4 { _Float16 h[4]; uint2 u; };

// kraus fp32 -> fp16, layout [L][K][2][64][64] (plane 0 = re, 1 = im)
__global__ void kconv_kernel(const float* __restrict__ re, const float* __restrict__ im,
                             _Float16* __restrict__ out) {
    int plane = blockIdx.y;
    int idx = blockIdx.x * blockDim.x + threadIdx.x;
    const float* src = plane ? im : re;
    float4 v = ((const float4*)src)[idx];
    int e = idx * 4;
    int lk = e >> 12;
    int rem = e & 4095;
    Pack4 p;
    p.h[0] = (_Float16)v.x; p.h[1] = (_Float16)v.y;
    p.h[2] = (_Float16)v.z; p.h[3] = (_Float16)v.w;
    *(uint2*)(out + ((size_t)lk * 2 + plane) * 4096 + rem) = p.u;
}

// state fp32 -> fp16 transposed: out[b][plane][l][j] = state[b][j][l]
__global__ void sconv_kernel(const float* __restrict__ re, const float* __restrict__ im,
                             _Float16* __restrict__ out) {
    __shared__ float tile[64][65];
    int b = blockIdx.x;
    int t = threadIdx.x;
    for (int plane = 0; plane < 2; ++plane) {
        const float* src = (plane ? im : re) + (size_t)b * 4096;
        __syncthreads();
        #pragma unroll
        for (int i = 0; i < 16; ++i) {
            int e = t + 256 * i;
            tile[e >> 6][e & 63] = src[e];
        }
        __syncthreads();
        _Float16* o = out + ((size_t)b * 2 + plane) * 4096;
        #pragma unroll
        for (int i = 0; i < 16; ++i) {
            int e = t + 256 * i;            // e = l*64 + j
            o[e] = (_Float16)tile[e & 63][e >> 6];
        }
    }
}

// One block per b; 4 waves; each wave owns one 32x32 tile (wr = row-half, wc = col-half).
// rho_in layout [b][plane][l][j] = rho^T (fp16).
// Per kraus k: stage1 Tt = rho^T * K^T with A1 = rho^T (hoisted regs), B1 = K rows;
// D1 -> Trow (T row-major, LDS); stage2 rho_new += T * K^dagger (fp32 acc, 32x32x16 MFMA).
__global__ __launch_bounds__(256, 4) void layer_kernel(
    const _Float16* __restrict__ rho_in,
    _Float16* __restrict__ rho_out,
    float* __restrict__ final_out,
    const _Float16* __restrict__ kraus,   // this layer: [K][2][64][64]
    int last)
{
    __shared__ __align__(16) _Float16 Klds[2][D][LSTR];
    __shared__ __align__(16) _Float16 Trow[2][D][LSTR];

    const int b    = blockIdx.x;
    const int t    = threadIdx.x;
    const int wv   = t >> 6;
    const int lane = t & 63;
    const int l31  = lane & 31;
    const int hl   = lane >> 5;
    const int wr   = wv >> 1;   // row half (stage1: l-range, stage2: i-range)
    const int wc   = wv & 1;    // col half (stage1: i-range, stage2: m-range)

    // ---- hoisted A1 fragments: rho^T row l = 32*wr + l31, j = 16*ks + 8*hl ----
    half8 a1re[4], a1im[4];
    {
        const _Float16* rb = rho_in + (size_t)b * 2 * D * D;
        const int row = 32 * wr + l31;
        #pragma unroll
        for (int ks = 0; ks < 4; ++ks) {
            const int col = 16 * ks + 8 * hl;
            a1re[ks] = *(const half8*)(rb + row * D + col);
            a1im[ks] = *(const half8*)(rb + D * D + row * D + col);
        }
    }

    f32x16 accRe, accIm;
    #pragma unroll
    for (int i = 0; i < 16; ++i) { accRe[i] = 0.f; accIm[i] = 0.f; }

    #pragma unroll 1
    for (int k = 0; k < NKR; ++k) {
        // ---- stage K_k into padded LDS ----
        const uint4* kg = (const uint4*)(kraus + (size_t)k * 2 * D * D); // 1024 x 16B
        #pragma unroll
        for (int r = 0; r < 4; ++r) {
            int idx = t + 256 * r;
            int e0  = idx * 8;
            int plane = e0 >> 12;
            int rem   = e0 & 4095;
            *(uint4*)&Klds[plane][rem >> 6][rem & 63] = kg[idx];
        }
        __syncthreads();

        // ---- stage 1: Tt tile (rows l in [32wr,+32), cols i in [32wc,+32)) ----
        f32x16 dre, dim;
        #pragma unroll
        for (int i = 0; i < 16; ++i) { dre[i] = 0.f; dim[i] = 0.f; }
        #pragma unroll
        for (int ks = 0; ks < 4; ++ks) {
            const int jcol = 16 * ks + 8 * hl;
            half8 bre  = *(const half8*)&Klds[0][32 * wc + l31][jcol];
            half8 bim  = *(const half8*)&Klds[1][32 * wc + l31][jcol];
            half8 bimn = neg8(bim);
            dre = __builtin_amdgcn_mfma_f32_32x32x16_f16(a1re[ks], bre,  dre, 0, 0, 0);
            dre = __builtin_amdgcn_mfma_f32_32x32x16_f16(a1im[ks], bimn, dre, 0, 0, 0);
            dim = __builtin_amdgcn_mfma_f32_32x32x16_f16(a1re[ks], bim,  dim, 0, 0, 0);
            dim = __builtin_amdgcn_mfma_f32_32x32x16_f16(a1im[ks], bre,  dim, 0, 0, 0);
        }
        // D1: col i = 32wc + l31; reg r=4g+j -> row l = 32wr + 8g + 4hl + j. Store Trow[i][l].
        {
            const int i = 32 * wc + l31;
            #pragma unroll
            for (int g = 0; g < 4; ++g) {
                Pack4 pr, pi;
                #pragma unroll
                for (int j = 0; j < 4; ++j) {
                    pr.h[j] = (_Float16)dre[4 * g + j];
                    pi.h[j] = (_Float16)dim[4 * g + j];
                }
                const int l0 = 32 * wr + 8 * g + 4 * hl;
                *(uint2*)&Trow[0][i][l0] = pr.u;
                *(uint2*)&Trow[1][i][l0] = pi.u;
            }
        }
        __syncthreads();

        // ---- stage 2: rho_new tile (rows i in [32wr,+32), cols m in [32wc,+32)) ----
        #pragma unroll
        for (int ks = 0; ks < 4; ++ks) {
            const int lcol = 16 * ks + 8 * hl;
            half8 are  = *(const half8*)&Trow[0][32 * wr + l31][lcol];
            half8 aim  = *(const half8*)&Trow[1][32 * wr + l31][lcol];
            half8 bre  = *(const half8*)&Klds[0][32 * wc + l31][lcol];
            half8 bim  = *(const half8*)&Klds[1][32 * wc + l31][lcol];
            half8 bimn = neg8(bim);
            accRe = __builtin_amdgcn_mfma_f32_32x32x16_f16(are, bre,  accRe, 0, 0, 0);
            accRe = __builtin_amdgcn_mfma_f32_32x32x16_f16(aim, bim,  accRe, 0, 0, 0);
            accIm = __builtin_amdgcn_mfma_f32_32x32x16_f16(aim, bre,  accIm, 0, 0, 0);
            accIm = __builtin_amdgcn_mfma_f32_32x32x16_f16(are, bimn, accIm, 0, 0, 0);
        }
        __syncthreads();   // protect Klds/Trow before next iteration's writes
    }

    // ---- epilogue: col m = 32wc + l31; reg r=4g+j -> row i = 32wr + 8g + 4hl + j ----
    if (!last) {
        _Float16* ob = rho_out + (size_t)b * 2 * D * D;
        const int m = 32 * wc + l31;
        #pragma unroll
        for (int g = 0; g < 4; ++g) {
            Pack4 pr, pi;
            #pragma unroll
            for (int j = 0; j < 4; ++j) {
                pr.h[j] = (_Float16)accRe[4 * g + j];
                pi.h[j] = (_Float16)accIm[4 * g + j];
            }
            const int i0 = 32 * wr + 8 * g + 4 * hl;
            *(uint2*)(ob + m * D + i0)         = pr.u;   // rho_new^T[m][i]
            *(uint2*)(ob + D * D + m * D + i0) = pi.u;
        }
    } else {
        float* o0 = final_out + (size_t)b * 4096;            // [0][b][i][m]
        float* o1 = final_out + (size_t)(NB + b) * 4096;     // [1][b][i][m]
        const int m = 32 * wc + l31;
        #pragma unroll
        for (int g = 0; g < 4; ++g) {
            #pragma unroll
            for (int j = 0; j < 4; ++j) {
                const int i = 32 * wr + 8 * g + 4 * hl + j;
                o0[i * D + m] = accRe[4 * g + j];
                o1[i * D + m] = accIm[4 * g + j];
            }
        }
    }
}

extern "C" void kernel_launch(void* const* d_in, const int* in_sizes, int n_in,
                              void* d_out, int out_size, void* d_ws, size_t ws_size,
                              hipStream_t stream) {
    const float* state_re = (const float*)d_in[0];
    const float* state_im = (const float*)d_in[1];
    const float* kraus_re = (const float*)d_in[2];
    const float* kraus_im = (const float*)d_in[3];

    _Float16* kraus_h = (_Float16*)d_ws;                         // 2 MB in ws
    // ping-pong rho buffers live inside d_out (2 x 16 MB = out_size exactly).
    _Float16* bufA = (_Float16*)d_out;
    _Float16* bufB = (_Float16*)((char*)d_out + (size_t)NB * 2 * D * D * sizeof(_Float16));
    float* fout = (float*)d_out;

    kconv_kernel<<<dim3(512, 2), 256, 0, stream>>>(kraus_re, kraus_im, kraus_h);
    sconv_kernel<<<NB, 256, 0, stream>>>(state_re, state_im, bufA);

    for (int l = 0; l < NL; ++l) {
        const _Float16* in = (l & 1) ? bufB : bufA;
        _Float16* out      = (l & 1) ? bufA : bufB;
        layer_kernel<<<NB, 256, 0, stream>>>(in, out, fout,
                                             kraus_h + (size_t)l * NKR * 2 * D * D,
                                             (l == NL - 1) ? 1 : 0);
    }
}